// Round 6
// baseline (418.989 us; speedup 1.0000x reference)
//
#include <hip/hip_runtime.h>
#include <hip/hip_bf16.h>

// ConceptBottleneck fused kernel, MI355X (gfx950).
// B=8192, IN=768, C=64, H=64, E=16.  Inputs/outputs fp32; internal math bf16 MFMA.
// cb_fused_t: grid (B/128, C); block = 128-row batch tile x one concept, 4 waves.
//   R6: 2Mx2N WAVE SPLIT + REGISTERED-A PREFETCH.
//   Calibration (R3 obs 27% = model 28%): L1 is LDS-READ-pipe bound; per-wave
//   B-read cost amortizes only over the wave's M rows. So:
//   - Wave w owns rows (w&1)*64 x bank (w>>1) 64 cols: B-reads 8 b128/iter
//     (was 16-20), MFMAs 32/iter -> LDS ~2.6 cyc/MFMA -> MfmaUtil ceiling ~46%.
//   - A (x) in REGISTERS av[4][2], loaded direct from global; loads for kt+1
//     are issued at the END of iter kt (after the MFMAs that read av), so they
//     fly across both barriers and are consumed next iter (R5's failure was
//     same-iteration consume = exposed L2 latency).  vmcnt ledger: top of iter
//     kt issues W(kt+1) glls; outstanding = W(kt)4+A(kt)4+W(kt+1)4=12 ->
//     s_waitcnt vmcnt(4) retires exactly W(kt)+A(kt). Never 0 in loop.
//   - W1 tiles: gll dbuf wbuf[2][128x64], XOR-swizzled source/reads (verified
//     R2/R3/R5 involution). 4 glls/wave/iter.
//   - Tail: per-wave SINGLE-bank chain (rows rb, bank b) -> acc pressure halved
//     vs R5; B operands direct-from-global preloaded into regs BEFORE each
//     epilogue (latency hides under epi VALU). One barrier before the cp phase
//     (32-row ownership), one before gate/output.
//   LDS 43520 B -> 3 blocks/CU (12 waves).  av crosses barriers: deliberate
//   bounded test of the prev-session "spill law" (~130 VGPR vs 170 cap);
//   spill detector = WRITE_SIZE bloat.

#define B_   8192
#define IN_  768
#define C_   64
#define H_   64
#define E_   16
#define BM_  128

typedef __bf16 bf16x8 __attribute__((ext_vector_type(8)));
typedef float  f32x4  __attribute__((ext_vector_type(4)));

__device__ __forceinline__ f32x4 mfma16(bf16x8 a, bf16x8 b, f32x4 c) {
  return __builtin_amdgcn_mfma_f32_16x16x32_bf16(a, b, c, 0, 0, 0);
}

__device__ __forceinline__ bf16x8 cvt8(float4 a, float4 b) {
  bf16x8 r;
  r[0] = (__bf16)a.x; r[1] = (__bf16)a.y; r[2] = (__bf16)a.z; r[3] = (__bf16)a.w;
  r[4] = (__bf16)b.x; r[5] = (__bf16)b.y; r[6] = (__bf16)b.z; r[7] = (__bf16)b.w;
  return r;
}

// 16B global -> LDS direct (vmcnt-counted; LDS dest = wave-uniform base + lane*16)
__device__ __forceinline__ void gll16(const __bf16* g, __bf16* l) {
  __builtin_amdgcn_global_load_lds(
      (const __attribute__((address_space(1))) unsigned int*)g,
      (__attribute__((address_space(3))) unsigned int*)l, 16, 0, 0);
}

#define FENCE asm volatile("" ::: "memory")

// ============================ MAIN KERNEL ===================================
// LDS (43520 B -> 3 blocks/CU):
//  wbuf[2][128*64] : L1 W1 dbuf (rows 0-63 pos, 64-127 neg), XOR-swizzled.
//                    Tail alias: hbP = wbuf[0], hbN = wbuf[1] ([128][64] swz).
//  xcb[128][40]    : pos|neg embeddings (cols 0..15 pos, 16..31 neg)
//  conc[128]       : concept logits
struct __align__(16) SmemT {
  __bf16 wbuf[2 * 128 * 64];
  __bf16 xcb[BM_ * 40];
  float  conc[BM_];
};
static_assert(sizeof(SmemT) == 43520, "layout");
static_assert(sizeof(SmemT) <= 54613, "LDS: need 3 blocks/CU");

// Epilogue to stride-64 XOR-swizzled buffer: col=nt*16+l16, row=rb+mt*16+quad*4+r.
// Slot for global chunk g at row = g^(row&7).
template <int MT>
__device__ __forceinline__ void epi64s(__bf16* hb, f32x4 (&acc)[MT][4],
                                       const float* __restrict__ bias,
                                       int rb, int quad, int l16) {
#pragma unroll
  for (int nt = 0; nt < 4; ++nt) {
    const int ch = nt * 2 + (l16 >> 3);
    const int cl = l16 & 7;
    const float bv = bias[nt * 16 + l16];
#pragma unroll
    for (int mt = 0; mt < MT; ++mt)
#pragma unroll
      for (int r = 0; r < 4; ++r) {
        const int row = rb + mt * 16 + quad * 4 + r;
        hb[row * 64 + (((ch ^ (row & 7)) << 3) | cl)] =
            (__bf16)fmaxf(acc[mt][nt][r] + bv, 0.f);
      }
  }
}

// L1 MFMA step: A from registers, B from swizzled wbuf bank-half (64 rows).
__device__ __forceinline__ void l1_step(const __bf16* wb, const bf16x8 (&av)[4][2],
                                        f32x4 (&acc)[4][4], int quad, int l16) {
  const int sx = l16 & 7;
#pragma unroll
  for (int ks = 0; ks < 2; ++ks) {
    const int pc = ((ks * 4 + quad) ^ sx) * 8;
    bf16x8 bb[4];
#pragma unroll
    for (int nt = 0; nt < 4; ++nt)
      bb[nt] = *(const bf16x8*)(wb + (nt * 16 + l16) * 64 + pc);
#pragma unroll
    for (int mt = 0; mt < 4; ++mt)
#pragma unroll
      for (int nt = 0; nt < 4; ++nt)
        acc[mt][nt] = mfma16(av[mt][ks], bb[nt], acc[mt][nt]);
  }
}

__global__ __launch_bounds__(256, 3) void cb_fused_t(
    const __bf16* __restrict__ x,
    const __bf16* __restrict__ pW1t, const float* __restrict__ pb1,
    const __bf16* __restrict__ pW2t, const float* __restrict__ pb2,
    const __bf16* __restrict__ pW3t, const float* __restrict__ pb3,
    const __bf16* __restrict__ nW1t, const float* __restrict__ nb1,
    const __bf16* __restrict__ nW2t, const float* __restrict__ nb2,
    const __bf16* __restrict__ nW3t, const float* __restrict__ nb3,
    const __bf16* __restrict__ cW1t, const float* __restrict__ cb1,
    const __bf16* __restrict__ cW2t, const float* __restrict__ cb2,
    const __bf16* __restrict__ cw3,  const float* __restrict__ cb3,
    float* __restrict__ out_emb, float* __restrict__ out_con)
{
  __shared__ SmemT sm;
  const int tid  = threadIdx.x;
  const int wave = tid >> 6, lane = tid & 63;
  const int quad = lane >> 4, l16 = lane & 15;
  const int bank = wave >> 1;          // 0 = pos, 1 = neg
  const int rb   = (wave & 1) * 64;    // A-row base (64 rows per wave)
  const int row0 = blockIdx.x * BM_;
  const int c    = blockIdx.y;

  const __bf16* pg = pW1t + (size_t)c * 64 * IN_;
  const __bf16* ng = nW1t + (size_t)c * 64 * IN_;

  // ---------- layer 1: A registered (prefetch 1 iter), W1 gll dbuf ----------
  f32x4 acc[4][4];
  {
    const f32x4 z = {0.f, 0.f, 0.f, 0.f};
#pragma unroll
    for (int mt = 0; mt < 4; ++mt)
#pragma unroll
      for (int nt = 0; nt < 4; ++nt) acc[mt][nt] = z;
  }

  const __bf16* xg = x + (size_t)row0 * IN_;
  const int lrow = lane >> 3, lchunk = (lane & 7) ^ lrow;  // swizzled gll source
  const __bf16* wsrc = (wave < 2)
      ? pg + (size_t)(wave * 32 + lrow) * IN_ + lchunk * 8
      : ng + (size_t)((wave - 2) * 32 + lrow) * IN_ + lchunk * 8;
  __bf16* const d0 = sm.wbuf + wave * 32 * 64;
  __bf16* const d1 = sm.wbuf + 8192 + wave * 32 * 64;
  const __bf16* ag = xg + (size_t)(rb + l16) * IN_ + quad * 8;

  bf16x8 av[4][2];
  // prologue: W(0) glls then A(0) loads (issue order fixes the vmcnt ledger)
#pragma unroll
  for (int j = 0; j < 4; ++j)
    gll16(wsrc + j * 8 * IN_, d0 + j * 8 * 64);
  __builtin_amdgcn_sched_barrier(0);
#pragma unroll
  for (int mt = 0; mt < 4; ++mt)
#pragma unroll
    for (int ks = 0; ks < 2; ++ks)
      av[mt][ks] = *(const bf16x8*)(ag + (size_t)mt * 16 * IN_ + ks * 32);
  __builtin_amdgcn_sched_barrier(0);

  for (int kt = 0; kt < 12; ++kt) {
    if (kt < 11) {
      const __bf16* wk = wsrc + (kt + 1) * 64;
      __bf16* nd = ((kt + 1) & 1) ? d1 : d0;
#pragma unroll
      for (int j = 0; j < 4; ++j)
        gll16(wk + j * 8 * IN_, nd + j * 8 * 64);
      // outstanding: W(kt)4 + A(kt)4 + W(kt+1)4 = 12 -> retire W(kt)+A(kt)
      asm volatile("s_waitcnt vmcnt(4)" ::: "memory");
    } else {
      // outstanding: W(11)4 + A(11)4
      asm volatile("s_waitcnt vmcnt(0)" ::: "memory");
    }
    __builtin_amdgcn_s_barrier();
    __builtin_amdgcn_sched_barrier(0);
    FENCE;
    l1_step(sm.wbuf + (kt & 1) * 8192 + bank * 4096, av, acc, quad, l16);
    FENCE;
    __builtin_amdgcn_sched_barrier(0);
    if (kt < 11) {
      // A(kt+1): issued AFTER the MFMAs that read av; in flight across barriers
#pragma unroll
      for (int mt = 0; mt < 4; ++mt)
#pragma unroll
        for (int ks = 0; ks < 2; ++ks)
          av[mt][ks] = *(const bf16x8*)(ag + (size_t)mt * 16 * IN_ +
                                        (kt + 1) * 64 + ks * 32);
    }
    __builtin_amdgcn_sched_barrier(0);
    __builtin_amdgcn_s_barrier();   // all reads of buf[(kt+1)&1] done (prev iter)
    __builtin_amdgcn_sched_barrier(0);
    FENCE;
  }

  // ---------- tail: wave-local (64 rows x own bank), B direct from L2 ----------
  __bf16* hbP = sm.wbuf;           // buf0 dead after kt=10 + barriers
  __bf16* hbN = sm.wbuf + 8192;    // buf1 dead after kt=11 + barrier
  __bf16* hbX = bank ? hbN : hbP;
  const __bf16* W2g = (bank ? nW2t : pW2t) + (size_t)c * 4096;
  const __bf16* W3g = (bank ? nW3t : pW3t) + (size_t)c * 1024;
  const float*  b1c = (bank ? nb1 : pb1) + c * 64;
  const float*  b2c = (bank ? nb2 : pb2) + c * 64;
  const float*  b3c = (bank ? nb3 : pb3) + c * 16;
  const int s7 = l16 & 7;

  // preload L2 B; latency hides under h1 epilogue
  bf16x8 bb2[2][4];
#pragma unroll
  for (int ks = 0; ks < 2; ++ks)
#pragma unroll
    for (int nt = 0; nt < 4; ++nt)
      bb2[ks][nt] = *(const bf16x8*)(W2g + (nt * 16 + l16) * 64 + ks * 32 + quad * 8);

  epi64s<4>(hbX, acc, b1c, rb, quad, l16);   // h1 -> hbX rows rb..rb+64

  // L2: [64,64] @ [64,64]
  f32x4 acc2[4][4];
  {
    const f32x4 z = {0.f, 0.f, 0.f, 0.f};
#pragma unroll
    for (int mt = 0; mt < 4; ++mt)
#pragma unroll
      for (int nt = 0; nt < 4; ++nt) acc2[mt][nt] = z;
  }
#pragma unroll
  for (int ks = 0; ks < 2; ++ks) {
    const int off = ((ks * 4 + quad) ^ s7) * 8;
    bf16x8 a[4];
#pragma unroll
    for (int mt = 0; mt < 4; ++mt)
      a[mt] = *(const bf16x8*)(hbX + (rb + mt * 16 + l16) * 64 + off);
#pragma unroll
    for (int mt = 0; mt < 4; ++mt)
#pragma unroll
      for (int nt = 0; nt < 4; ++nt)
        acc2[mt][nt] = mfma16(a[mt], bb2[ks][nt], acc2[mt][nt]);
  }

  // preload L3 B; hides under h2 epilogue
  bf16x8 bb3[2];
#pragma unroll
  for (int ks = 0; ks < 2; ++ks)
    bb3[ks] = *(const bf16x8*)(W3g + l16 * 64 + ks * 32 + quad * 8);

  epi64s<4>(hbX, acc2, b2c, rb, quad, l16);  // h2 -> hbX

  // L3: e = h2 @ W3^T -> xcb[:, bank*16 + 0..16)
  {
    f32x4 acc3[4];
    const f32x4 z = {0.f, 0.f, 0.f, 0.f};
#pragma unroll
    for (int mt = 0; mt < 4; ++mt) acc3[mt] = z;
#pragma unroll
    for (int ks = 0; ks < 2; ++ks) {
      const int off = ((ks * 4 + quad) ^ s7) * 8;
#pragma unroll
      for (int mt = 0; mt < 4; ++mt) {
        bf16x8 a = *(const bf16x8*)(hbX + (rb + mt * 16 + l16) * 64 + off);
        acc3[mt] = mfma16(a, bb3[ks], acc3[mt]);
      }
    }
    const float bv = b3c[l16];
#pragma unroll
    for (int mt = 0; mt < 4; ++mt)
#pragma unroll
      for (int r = 0; r < 4; ++r) {
        const int row = rb + mt * 16 + quad * 4 + r;
        sm.xcb[row * 40 + bank * 16 + l16] = (__bf16)(acc3[mt][r] + bv);
      }
  }
  __syncthreads();   // xcb (cross-wave) + hbP WAR for cp scratch

  // ---------- cp phase: rows r2 = wave*32 ----------
  const int r2 = wave * 32;
  {
    // cp1: [32,32] @ [32,64]; A = xcb (stride 40), B = cW1t [64][32] direct
    const __bf16* c1 = cW1t + (size_t)c * 2048;
    bf16x8 bc1[4];
#pragma unroll
    for (int nt = 0; nt < 4; ++nt)
      bc1[nt] = *(const bf16x8*)(c1 + (nt * 16 + l16) * 32 + quad * 8);
    f32x4 acc1[2][4];
    {
      const f32x4 z = {0.f, 0.f, 0.f, 0.f};
#pragma unroll
      for (int mt = 0; mt < 2; ++mt)
#pragma unroll
        for (int nt = 0; nt < 4; ++nt) acc1[mt][nt] = z;
    }
    bf16x8 a1[2];
#pragma unroll
    for (int mt = 0; mt < 2; ++mt)
      a1[mt] = *(const bf16x8*)&sm.xcb[(r2 + mt * 16 + l16) * 40 + quad * 8];
#pragma unroll
    for (int mt = 0; mt < 2; ++mt)
#pragma unroll
      for (int nt = 0; nt < 4; ++nt)
        acc1[mt][nt] = mfma16(a1[mt], bc1[nt], acc1[mt][nt]);

    // preload cp2 B; hides under cp1 epilogue
    const __bf16* c2 = cW2t + (size_t)c * 4096;
    bf16x8 bc2[2][4];
#pragma unroll
    for (int ks = 0; ks < 2; ++ks)
#pragma unroll
      for (int nt = 0; nt < 4; ++nt)
        bc2[ks][nt] = *(const bf16x8*)(c2 + (nt * 16 + l16) * 64 + ks * 32 + quad * 8);

    epi64s<2>(hbP, acc1, cb1 + c * 64, r2, quad, l16);

    // cp2
    f32x4 accC[2][4];
    {
      const f32x4 z = {0.f, 0.f, 0.f, 0.f};
#pragma unroll
      for (int mt = 0; mt < 2; ++mt)
#pragma unroll
        for (int nt = 0; nt < 4; ++nt) accC[mt][nt] = z;
    }
#pragma unroll
    for (int ks = 0; ks < 2; ++ks) {
      const int off = ((ks * 4 + quad) ^ s7) * 8;
      bf16x8 a[2];
#pragma unroll
      for (int mt = 0; mt < 2; ++mt)
        a[mt] = *(const bf16x8*)(hbP + (r2 + mt * 16 + l16) * 64 + off);
#pragma unroll
      for (int mt = 0; mt < 2; ++mt)
#pragma unroll
        for (int nt = 0; nt < 4; ++nt)
          accC[mt][nt] = mfma16(a[mt], bc2[ks][nt], accC[mt][nt]);
    }
    epi64s<2>(hbP, accC, cb2 + c * 64, r2, quad, l16);

    // cp3 (N=1 via MFMA; B nonzero only in lane col 0)
    f32x4 acc3b[2];
    {
      const f32x4 z = {0.f, 0.f, 0.f, 0.f};
      acc3b[0] = z; acc3b[1] = z;
    }
#pragma unroll
    for (int ks = 0; ks < 2; ++ks) {
      const int off = ((ks * 4 + quad) ^ s7) * 8;
      bf16x8 bbv = {};
      if (l16 == 0) bbv = *(const bf16x8*)(cw3 + (size_t)c * 64 + ks * 32 + quad * 8);
#pragma unroll
      for (int mt = 0; mt < 2; ++mt) {
        bf16x8 a = *(const bf16x8*)(hbP + (r2 + mt * 16 + l16) * 64 + off);
        acc3b[mt] = mfma16(a, bbv, acc3b[mt]);
      }
    }
    if (l16 == 0) {
      float bv = cb3[c];
#pragma unroll
      for (int mt = 0; mt < 2; ++mt)
#pragma unroll
        for (int r = 0; r < 4; ++r)
          sm.conc[r2 + mt * 16 + quad * 4 + r] = acc3b[mt][r] + bv;
    }
  }
  __syncthreads();   // conc + xcb needed cross-wave

  // ---- gate + outputs (fp32) ----
  for (int ii = tid; ii < BM_ * E_; ii += 256) {
    int row = ii >> 4, e = ii & 15;
    float cv = sm.conc[row];
    float w  = fminf(fmaxf(cv * 0.5f + 0.5f, 0.f), 1.f);
    float pv2 = (float)sm.xcb[row * 40 + e];
    float nv2 = (float)sm.xcb[row * 40 + 16 + e];
    out_emb[(size_t)(row0 + row) * (E_ * C_) + e * C_ + c] = pv2 * w + nv2 * (1.f - w);
  }
  if (tid < 128) out_con[(size_t)(row0 + tid) * C_ + c] = sm.conc[tid];
}

// ------------- prep_all: ONE flat 1D launch, no dead blocks -------------------
#define TSEG 5
#define PSEG 5
struct PrepArgs {
  const float* tsrc[TSEG];
  __bf16*      tdst[TSEG];
  int tstart[TSEG + 1];
  int ktiles[TSEG];            // K/64
  const float* psrc[PSEG];
  __bf16*      pdst[PSEG];
  int pstart[PSEG + 1];        // block starts (after tblocks)
  int pchunks[PSEG];           // total 8-elem chunks in segment
  int kdiv8[PSEG];
  int N[PSEG];                 // 1 = plain copy, else transpose inner stride
  int tblocks;
};

__global__ __launch_bounds__(256) void prep_all(PrepArgs a) {
  const int tid = threadIdx.x;
  const int b = blockIdx.x;
  __shared__ __bf16 lt[64 * 72];
  if (b < a.tblocks) {
    int s = 0;
    while (s < TSEG - 1 && b >= a.tstart[s + 1]) ++s;
    const int idx = b - a.tstart[s];
    const int kt = idx % a.ktiles[s];
    const int c  = idx / a.ktiles[s];
    const int K  = a.ktiles[s] * 64;
    const float* src = a.tsrc[s] + (size_t)c * K * 64 + (size_t)kt * 64 * 64;
    __bf16*      dst = a.tdst[s] + (size_t)c * 64 * K + kt * 64;
    const int r = tid >> 4, c4 = (tid & 15) * 4;
#pragma unroll
    for (int it = 0; it < 4; ++it) {
      int k = r + it * 16;
      float4 v = *(const float4*)(src + (size_t)k * 64 + c4);
      lt[(c4 + 0) * 72 + k] = (__bf16)v.x;
      lt[(c4 + 1) * 72 + k] = (__bf16)v.y;
      lt[(c4 + 2) * 72 + k] = (__bf16)v.z;
      lt[(c4 + 3) * 72 + k] = (__bf16)v.w;
    }
    __syncthreads();
    const int n = tid >> 3, i = tid & 7;
#pragma unroll
    for (int it = 0; it < 2; ++it) {
      int nn = n + it * 32;
      *(uint4*)(dst + (size_t)nn * K + i * 8) = *(const uint4*)&lt[nn * 72 + i * 8];
    }
  } else {
    const int bb = b - a.tblocks;
    int s = 0;
    while (s < PSEG - 1 && bb >= a.pstart[s + 1]) ++s;
    const int lb  = bb - a.pstart[s];
    const int nch = a.pchunks[s];
    const int kc  = a.kdiv8[s];
    const int N   = a.N[s];
#pragma unroll
    for (int j = 0; j < 4; ++j) {
      const int li = (lb * 4 + j) * 256 + tid;
      if (li >= nch) break;
      if (N == 1) {
        const float4* src = (const float4*)a.psrc[s] + (size_t)li * 2;
        float4 v0 = src[0], v1 = src[1];
        *(uint4*)(a.pdst[s] + (size_t)li * 8) = __builtin_bit_cast(uint4, cvt8(v0, v1));
      } else {
        int rn = li / kc;
        int k0 = (li - rn * kc) * 8;
        int cc = rn / N;
        int n  = rn - cc * N;
        const float* src = a.psrc[s] + ((size_t)cc * kc * 8 + k0) * N + n;
        bf16x8 r;
#pragma unroll
        for (int jj = 0; jj < 8; ++jj) r[jj] = (__bf16)src[(size_t)jj * N];
        *(uint4*)(a.pdst[s] + (size_t)rn * kc * 8 + k0) = __builtin_bit_cast(uint4, r);
      }
    }
  }
}

// ============================== launch =======================================
extern "C" void kernel_launch(void* const* d_in, const int* in_sizes, int n_in,
                              void* d_out, int out_size, void* d_ws, size_t ws_size,
                              hipStream_t stream) {
  const float* xf   = (const float*)d_in[0];
  const float* pW1f = (const float*)d_in[1];
  const float* pb1f = (const float*)d_in[2];
  const float* pW2f = (const float*)d_in[3];
  const float* pb2f = (const float*)d_in[4];
  const float* pW3f = (const float*)d_in[5];
  const float* pb3f = (const float*)d_in[6];
  const float* nW1f = (const float*)d_in[7];
  const float* nb1f = (const float*)d_in[8];
  const float* nW2f = (const float*)d_in[9];
  const float* nb2f = (const float*)d_in[10];
  const float* nW3f = (const float*)d_in[11];
  const float* nb3f = (const float*)d_in[12];
  const float* cW1f = (const float*)d_in[13];
  const float* cb1f = (const float*)d_in[14];
  const float* cW2f = (const float*)d_in[15];
  const float* cb2f = (const float*)d_in[16];
  const float* cW3f = (const float*)d_in[17];
  const float* cb3f = (const float*)d_in[18];

  float* out_emb = (float*)d_out;
  float* out_con = out_emb + (size_t)B_ * E_ * C_;

  const int cx   = B_ * IN_;          // 6291456
  const int cW1c = C_ * IN_ * H_;     // 3145728
  const int cW2c = C_ * H_ * H_;      // 262144
  const int cW3c = C_ * H_ * E_;      // 65536
  const int ccW1 = C_ * 2 * E_ * H_;  // 131072
  const int ccW3 = C_ * H_;           // 4096

  __bf16* w = (__bf16*)d_ws;
  size_t o = 0;
  __bf16* xw   = w + o; o += cx;
  __bf16* pw1t = w + o; o += cW1c;
  __bf16* nw1t = w + o; o += cW1c;
  __bf16* pw2t = w + o; o += cW2c;
  __bf16* nw2t = w + o; o += cW2c;
  __bf16* cw2t = w + o; o += cW2c;
  __bf16* pw3t = w + o; o += cW3c;
  __bf16* nw3t = w + o; o += cW3c;
  __bf16* cw1t = w + o; o += ccW1;
  __bf16* cw3w = w + o; o += ccW3;

  PrepArgs a;
  int tb = 0, pb = 0;
  {
    const float* tsrc[TSEG] = {pW1f, nW1f, pW2f, nW2f, cW2f};
    __bf16*      tdst[TSEG] = {pw1t, nw1t, pw2t, nw2t, cw2t};
    const int    tk[TSEG]   = {12,   12,   1,    1,    1};
    for (int i = 0; i < TSEG; ++i) {
      a.tsrc[i] = tsrc[i]; a.tdst[i] = tdst[i]; a.ktiles[i] = tk[i];
      a.tstart[i] = tb;
      tb += tk[i] * C_;
    }
    a.tstart[TSEG] = tb;
    a.tblocks = tb;

    const float* psrc[PSEG] = {xf, cW3f, pW3f, nW3f, cW1f};
    __bf16*      pdst[PSEG] = {xw, cw3w, pw3t, nw3t, cw1t};
    const int    pKs[PSEG]  = {0,  0,    64,   64,   32};
    const int    pNs[PSEG]  = {1,  1,    16,   16,   64};
    const int    pels[PSEG] = {cx, ccW3, cW3c, cW3c, ccW1};
    for (int i = 0; i < PSEG; ++i) {
      a.psrc[i] = psrc[i]; a.pdst[i] = pdst[i];
      a.pchunks[i] = pels[i] / 8;
      a.kdiv8[i] = (pNs[i] == 1) ? (pels[i] / 8) : (pKs[i] / 8);
      a.N[i] = pNs[i];
      a.pstart[i] = pb;
      pb += (pels[i] / 8 + 1023) / 1024;   // 256 threads x 4 chunks per block
    }
    a.pstart[PSEG] = pb;
  }
  prep_all<<<tb + pb, 256, 0, stream>>>(a);

  dim3 grid(B_ / BM_, C_);
  cb_fused_t<<<grid, 256, 0, stream>>>(xw,
      pw1t, pb1f, pw2t, pb2f, pw3t, pb3f,
      nw1t, nb1f, nw2t, nb2f, nw3t, nb3f,
      cw1t, cb1f, cw2t, cb2f, cw3w, cb3f,
      out_emb, out_con);
}

// Round 7
// 314.862 us; speedup vs baseline: 1.3307x; 1.3307x over previous
//
#include <hip/hip_runtime.h>
#include <hip/hip_bf16.h>

// ConceptBottleneck fused kernel, MI355X (gfx950).
// B=8192, IN=768, C=64, H=64, E=16.  Inputs/outputs fp32; internal math bf16 MFMA.
// cb_fused_t: grid (B/128, C); block = 128-row batch tile x one concept, 4 waves.
//   R7: SINGLE-X-BUFFER + W-DBUF + 2Mx2N SPLIT -> 3 blocks/CU.
//   - LDS 49152 B: xs[128][64] (x tile, single buffer; tail: xcb+conc alias) +
//     wbuf[2][128][64] (W1 dbuf; tail: hbP/hbN). 3 blocks/CU, 12 waves.
//   - Wave w owns M rows rb=(w&1)*64 x bank=(w>>1) (pos/neg): 16 b128
//     reads/wave/iter (8 A + 8 B) for 32 MFMAs -- minimal read duplication (2x).
//   - Per iter kt: vmcnt(4) [x(kt) landed; W(kt) stays in flight -- never a
//     mid-pipe drain] -> s_barrier -> a-extract (8 ds_read -> regs; 32 VGPRs
//     cross ONE barrier: R6's counters proved AGPRs don't count against VGPR_
//     Count and no spill at (256,3)) -> __syncthreads (drains lgkm + W(kt)) ->
//     issue x(kt+1) glls into xs (now safe) + W(kt+1) glls into wbuf^1 ->
//     B-reads + 32 MFMA.  Issue-to-wait distance = one full MFMA phase
//     (R6 lesson: end-of-iter issue gave only ~50cy cover -> 316us).
//   - gll staging is COALESCED (128B rows, XOR-swizzled source, linear LDS,
//     swizzled reads -- R2/R3-verified involution). R5/R6 lesson: per-fragment
//     direct A loads are 64B-granule scattered -> L2 request pressure.
//   - Tail: wave-local bank-chains (R6-verified logic): h1->L2->h2->L3->xcb,
//     B operands preloaded direct-from-global (16 consecutive rows x 64B per
//     instr, L2-hot) before each epilogue; 1 barrier before cp phase, 1 before
//     gate/output.

#define B_   8192
#define IN_  768
#define C_   64
#define H_   64
#define E_   16
#define BM_  128

typedef __bf16 bf16x8 __attribute__((ext_vector_type(8)));
typedef float  f32x4  __attribute__((ext_vector_type(4)));

__device__ __forceinline__ f32x4 mfma16(bf16x8 a, bf16x8 b, f32x4 c) {
  return __builtin_amdgcn_mfma_f32_16x16x32_bf16(a, b, c, 0, 0, 0);
}

__device__ __forceinline__ bf16x8 cvt8(float4 a, float4 b) {
  bf16x8 r;
  r[0] = (__bf16)a.x; r[1] = (__bf16)a.y; r[2] = (__bf16)a.z; r[3] = (__bf16)a.w;
  r[4] = (__bf16)b.x; r[5] = (__bf16)b.y; r[6] = (__bf16)b.z; r[7] = (__bf16)b.w;
  return r;
}

// 16B global -> LDS direct (vmcnt-counted; LDS dest = wave-uniform base + lane*16)
__device__ __forceinline__ void gll16(const __bf16* g, __bf16* l) {
  __builtin_amdgcn_global_load_lds(
      (const __attribute__((address_space(1))) unsigned int*)g,
      (__attribute__((address_space(3))) unsigned int*)l, 16, 0, 0);
}

// ============================ MAIN KERNEL ===================================
// LDS (49152 B -> 3 blocks/CU):
//  xs  [128*64]    : L1 x tile (single buffer) | tail: xcb[128*40] + conc[128]
//  wbuf[2*128*64]  : W1 dbuf (rows 0-63 pos, 64-127 neg), XOR-swizzled
//                    | tail: hbP = wbuf[0:8192], hbN = wbuf[8192:]
struct __align__(16) SmemT {
  __bf16 xs[128 * 64];
  __bf16 wbuf[2 * 128 * 64];
};
static_assert(sizeof(SmemT) == 49152, "layout");
static_assert(sizeof(SmemT) <= 54613, "LDS: need 3 blocks/CU");

// Epilogue to stride-64 XOR-swizzled buffer: col=nt*16+l16, row=rb+mt*16+quad*4+r.
// Slot for global chunk g at row = g^(row&7).
template <int MT>
__device__ __forceinline__ void epi64s(__bf16* hb, f32x4 (&acc)[MT][4],
                                       const float* __restrict__ bias,
                                       int rb, int quad, int l16) {
#pragma unroll
  for (int nt = 0; nt < 4; ++nt) {
    const int ch = nt * 2 + (l16 >> 3);
    const int cl = l16 & 7;
    const float bv = bias[nt * 16 + l16];
#pragma unroll
    for (int mt = 0; mt < MT; ++mt)
#pragma unroll
      for (int r = 0; r < 4; ++r) {
        const int row = rb + mt * 16 + quad * 4 + r;
        hb[row * 64 + (((ch ^ (row & 7)) << 3) | cl)] =
            (__bf16)fmaxf(acc[mt][nt][r] + bv, 0.f);
      }
  }
}

__global__ __launch_bounds__(256, 3) void cb_fused_t(
    const __bf16* __restrict__ x,
    const __bf16* __restrict__ pW1t, const float* __restrict__ pb1,
    const __bf16* __restrict__ pW2t, const float* __restrict__ pb2,
    const __bf16* __restrict__ pW3t, const float* __restrict__ pb3,
    const __bf16* __restrict__ nW1t, const float* __restrict__ nb1,
    const __bf16* __restrict__ nW2t, const float* __restrict__ nb2,
    const __bf16* __restrict__ nW3t, const float* __restrict__ nb3,
    const __bf16* __restrict__ cW1t, const float* __restrict__ cb1,
    const __bf16* __restrict__ cW2t, const float* __restrict__ cb2,
    const __bf16* __restrict__ cw3,  const float* __restrict__ cb3,
    float* __restrict__ out_emb, float* __restrict__ out_con)
{
  __shared__ SmemT sm;
  const int tid  = threadIdx.x;
  const int wave = tid >> 6, lane = tid & 63;
  const int quad = lane >> 4, l16 = lane & 15;
  const int bank = wave >> 1;          // 0 = pos, 1 = neg
  const int rb   = (wave & 1) * 64;    // A-row base (64 rows per wave)
  const int s7   = l16 & 7;
  const int row0 = blockIdx.x * BM_;
  const int c    = blockIdx.y;

  const __bf16* pg = pW1t + (size_t)c * 64 * IN_;
  const __bf16* ng = nW1t + (size_t)c * 64 * IN_;

  // ---------- layer 1: single-x-buffer + W dbuf, 2Mx2N ----------
  f32x4 acc[4][4];
  {
    const f32x4 z = {0.f, 0.f, 0.f, 0.f};
#pragma unroll
    for (int mt = 0; mt < 4; ++mt)
#pragma unroll
      for (int nt = 0; nt < 4; ++nt) acc[mt][nt] = z;
  }

  const __bf16* xg = x + (size_t)row0 * IN_;
  const int lrow = lane >> 3;                 // 0..7 within 8-row gll group
  const int lchunk = (lane & 7) ^ lrow;       // swizzled source chunk
  // x: wave w stages rows w*32..+32 (4 glls of 8 rows)
  const __bf16* xsrc = xg + (size_t)(wave * 32 + lrow) * IN_ + lchunk * 8;
  // W: waves 0,1 -> pos rows 0-63; waves 2,3 -> neg rows 64-127 of tile
  const __bf16* wgsrc = (wave < 2)
      ? pg + (size_t)(wave * 32 + lrow) * IN_ + lchunk * 8
      : ng + (size_t)((wave - 2) * 32 + lrow) * IN_ + lchunk * 8;
  const int wdrow = (wave < 2) ? wave * 32 : 64 + (wave - 2) * 32;

  // prologue: x(0) first, then W(0) (issue order = vmcnt ledger order)
#pragma unroll
  for (int j = 0; j < 4; ++j)
    gll16(xsrc + j * 8 * IN_, sm.xs + (wave * 32 + j * 8) * 64);
  __builtin_amdgcn_sched_barrier(0);
#pragma unroll
  for (int j = 0; j < 4; ++j)
    gll16(wgsrc + j * 8 * IN_, sm.wbuf + (wdrow + j * 8) * 64);
  __builtin_amdgcn_sched_barrier(0);

  for (int kt = 0; kt < 12; ++kt) {
    // outstanding: x(kt)4 (oldest) + W(kt)4 -> retire x(kt), keep W(kt) flying
    asm volatile("s_waitcnt vmcnt(4)" ::: "memory");
    __builtin_amdgcn_s_barrier();             // xs = x(kt) valid block-wide
    __builtin_amdgcn_sched_barrier(0);
    // a-extract: 8 ds_read_b128 -> regs (live across ONE barrier)
    bf16x8 a[4][2];
#pragma unroll
    for (int mt = 0; mt < 4; ++mt)
#pragma unroll
      for (int ks = 0; ks < 2; ++ks)
        a[mt][ks] = *(const bf16x8*)(sm.xs + (rb + mt * 16 + l16) * 64 +
                                     (((ks * 4 + quad) ^ s7) << 3));
    __syncthreads();   // waitcnt lgkm(0) [a landed] + vmcnt(0) [W(kt) landed] + barrier
    __builtin_amdgcn_sched_barrier(0);
    if (kt < 11) {
      const int ko = (kt + 1) * 64;
      // x(kt+1) into xs (all waves extracted x(kt)); issue-to-wait = 1 MFMA phase
#pragma unroll
      for (int j = 0; j < 4; ++j)
        gll16(xsrc + j * 8 * IN_ + ko, sm.xs + (wave * 32 + j * 8) * 64);
      __builtin_amdgcn_sched_barrier(0);
      // W(kt+1) into the other W buffer (its last readers finished in kt-1,
      // two barriers ago)
      __bf16* wbn = sm.wbuf + ((kt + 1) & 1) * 8192;
#pragma unroll
      for (int j = 0; j < 4; ++j)
        gll16(wgsrc + j * 8 * IN_ + ko, wbn + (wdrow + j * 8) * 64);
    }
    __builtin_amdgcn_sched_barrier(0);
    // MFMA phase: B from wbuf[kt&1] (bank half), 32 MFMAs
    const __bf16* wb = sm.wbuf + (kt & 1) * 8192 + bank * 4096;
#pragma unroll
    for (int ks = 0; ks < 2; ++ks) {
      const int pc = ((ks * 4 + quad) ^ s7) << 3;
      bf16x8 bb[4];
#pragma unroll
      for (int nt = 0; nt < 4; ++nt)
        bb[nt] = *(const bf16x8*)(wb + (nt * 16 + l16) * 64 + pc);
#pragma unroll
      for (int mt = 0; mt < 4; ++mt)
#pragma unroll
        for (int nt = 0; nt < 4; ++nt)
          acc[mt][nt] = mfma16(a[mt][ks], bb[nt], acc[mt][nt]);
    }
  }
  __syncthreads();   // all kt=11 B-reads done; wbuf -> hb, xs -> xcb/conc

  // ---------- tail: wave-local bank-chains; B direct from L2 ----------
  __bf16* hbP  = sm.wbuf;           // [128][64] swz
  __bf16* hbN  = sm.wbuf + 8192;
  __bf16* hbX  = bank ? hbN : hbP;
  __bf16* xcb  = sm.xs;             // [128][40]
  float*  conc = (float*)(sm.xs + 5120);

  const __bf16* W2g = (bank ? nW2t : pW2t) + (size_t)c * 4096;
  const __bf16* W3g = (bank ? nW3t : pW3t) + (size_t)c * 1024;
  const float*  b1c = (bank ? nb1 : pb1) + c * 64;
  const float*  b2c = (bank ? nb2 : pb2) + c * 64;
  const float*  b3c = (bank ? nb3 : pb3) + c * 16;

  // preload L2 B (16 consecutive rows x 64B per instr; L2-hot); hides under epi
  bf16x8 bb2[2][4];
#pragma unroll
  for (int ks = 0; ks < 2; ++ks)
#pragma unroll
    for (int nt = 0; nt < 4; ++nt)
      bb2[ks][nt] = *(const bf16x8*)(W2g + (nt * 16 + l16) * 64 + ks * 32 + quad * 8);

  epi64s<4>(hbX, acc, b1c, rb, quad, l16);   // h1 -> hbX rows rb..rb+64

  // L2: [64,64] @ [64,64]
  f32x4 acc2[4][4];
  {
    const f32x4 z = {0.f, 0.f, 0.f, 0.f};
#pragma unroll
    for (int mt = 0; mt < 4; ++mt)
#pragma unroll
      for (int nt = 0; nt < 4; ++nt) acc2[mt][nt] = z;
  }
#pragma unroll
  for (int ks = 0; ks < 2; ++ks) {
    const int off = ((ks * 4 + quad) ^ s7) << 3;
    bf16x8 a[4];
#pragma unroll
    for (int mt = 0; mt < 4; ++mt)
      a[mt] = *(const bf16x8*)(hbX + (rb + mt * 16 + l16) * 64 + off);
#pragma unroll
    for (int mt = 0; mt < 4; ++mt)
#pragma unroll
      for (int nt = 0; nt < 4; ++nt)
        acc2[mt][nt] = mfma16(a[mt], bb2[ks][nt], acc2[mt][nt]);
  }

  // preload L3 B; hides under h2 epilogue
  bf16x8 bb3[2];
#pragma unroll
  for (int ks = 0; ks < 2; ++ks)
    bb3[ks] = *(const bf16x8*)(W3g + l16 * 64 + ks * 32 + quad * 8);

  epi64s<4>(hbX, acc2, b2c, rb, quad, l16);  // h2 -> hbX

  // L3: e = h2 @ W3^T -> xcb[:, bank*16 + 0..16)
  {
    f32x4 acc3[4];
    const f32x4 z = {0.f, 0.f, 0.f, 0.f};
#pragma unroll
    for (int mt = 0; mt < 4; ++mt) acc3[mt] = z;
#pragma unroll
    for (int ks = 0; ks < 2; ++ks) {
      const int off = ((ks * 4 + quad) ^ s7) << 3;
#pragma unroll
      for (int mt = 0; mt < 4; ++mt) {
        bf16x8 a = *(const bf16x8*)(hbX + (rb + mt * 16 + l16) * 64 + off);
        acc3[mt] = mfma16(a, bb3[ks], acc3[mt]);
      }
    }
    const float bv = b3c[l16];
#pragma unroll
    for (int mt = 0; mt < 4; ++mt)
#pragma unroll
      for (int r = 0; r < 4; ++r) {
        const int row = rb + mt * 16 + quad * 4 + r;
        xcb[row * 40 + bank * 16 + l16] = (__bf16)(acc3[mt][r] + bv);
      }
  }
  __syncthreads();   // xcb cross-wave; hbP/hbN dead -> cp scratch

  // ---------- cp phase: rows r2 = wave*32 ----------
  const int r2 = wave * 32;
  {
    // cp1: [32,32] @ [32,64]; A = xcb (stride 40), B = cW1t [64][32] direct
    const __bf16* c1 = cW1t + (size_t)c * 2048;
    bf16x8 bc1[4];
#pragma unroll
    for (int nt = 0; nt < 4; ++nt)
      bc1[nt] = *(const bf16x8*)(c1 + (nt * 16 + l16) * 32 + quad * 8);
    f32x4 acc1[2][4];
    {
      const f32x4 z = {0.f, 0.f, 0.f, 0.f};
#pragma unroll
      for (int mt = 0; mt < 2; ++mt)
#pragma unroll
        for (int nt = 0; nt < 4; ++nt) acc1[mt][nt] = z;
    }
    bf16x8 a1[2];
#pragma unroll
    for (int mt = 0; mt < 2; ++mt)
      a1[mt] = *(const bf16x8*)&xcb[(r2 + mt * 16 + l16) * 40 + quad * 8];
#pragma unroll
    for (int mt = 0; mt < 2; ++mt)
#pragma unroll
      for (int nt = 0; nt < 4; ++nt)
        acc1[mt][nt] = mfma16(a1[mt], bc1[nt], acc1[mt][nt]);

    // preload cp2 B; hides under cp1 epilogue
    const __bf16* c2 = cW2t + (size_t)c * 4096;
    bf16x8 bc2[2][4];
#pragma unroll
    for (int ks = 0; ks < 2; ++ks)
#pragma unroll
      for (int nt = 0; nt < 4; ++nt)
        bc2[ks][nt] = *(const bf16x8*)(c2 + (nt * 16 + l16) * 64 + ks * 32 + quad * 8);

    epi64s<2>(hbP, acc1, cb1 + c * 64, r2, quad, l16);

    // cp2
    f32x4 accC[2][4];
    {
      const f32x4 z = {0.f, 0.f, 0.f, 0.f};
#pragma unroll
      for (int mt = 0; mt < 2; ++mt)
#pragma unroll
        for (int nt = 0; nt < 4; ++nt) accC[mt][nt] = z;
    }
#pragma unroll
    for (int ks = 0; ks < 2; ++ks) {
      const int off = ((ks * 4 + quad) ^ s7) << 3;
      bf16x8 a[2];
#pragma unroll
      for (int mt = 0; mt < 2; ++mt)
        a[mt] = *(const bf16x8*)(hbP + (r2 + mt * 16 + l16) * 64 + off);
#pragma unroll
      for (int mt = 0; mt < 2; ++mt)
#pragma unroll
        for (int nt = 0; nt < 4; ++nt)
          accC[mt][nt] = mfma16(a[mt], bc2[ks][nt], accC[mt][nt]);
    }
    epi64s<2>(hbP, accC, cb2 + c * 64, r2, quad, l16);

    // cp3 (N=1 via MFMA; B nonzero only in lane col 0)
    f32x4 acc3b[2];
    {
      const f32x4 z = {0.f, 0.f, 0.f, 0.f};
      acc3b[0] = z; acc3b[1] = z;
    }
#pragma unroll
    for (int ks = 0; ks < 2; ++ks) {
      const int off = ((ks * 4 + quad) ^ s7) << 3;
      bf16x8 bbv = {};
      if (l16 == 0) bbv = *(const bf16x8*)(cw3 + (size_t)c * 64 + ks * 32 + quad * 8);
#pragma unroll
      for (int mt = 0; mt < 2; ++mt) {
        bf16x8 a = *(const bf16x8*)(hbP + (r2 + mt * 16 + l16) * 64 + off);
        acc3b[mt] = mfma16(a, bbv, acc3b[mt]);
      }
    }
    if (l16 == 0) {
      float bv = cb3[c];
#pragma unroll
      for (int mt = 0; mt < 2; ++mt)
#pragma unroll
        for (int r = 0; r < 4; ++r)
          conc[r2 + mt * 16 + quad * 4 + r] = acc3b[mt][r] + bv;
    }
  }
  __syncthreads();   // conc + xcb needed cross-wave

  // ---- gate + outputs (fp32) ----
  for (int ii = tid; ii < BM_ * E_; ii += 256) {
    int row = ii >> 4, e = ii & 15;
    float cv = conc[row];
    float w  = fminf(fmaxf(cv * 0.5f + 0.5f, 0.f), 1.f);
    float pv2 = (float)xcb[row * 40 + e];
    float nv2 = (float)xcb[row * 40 + 16 + e];
    out_emb[(size_t)(row0 + row) * (E_ * C_) + e * C_ + c] = pv2 * w + nv2 * (1.f - w);
  }
  if (tid < 128) out_con[(size_t)(row0 + tid) * C_ + c] = conc[tid];
}

// ------------- prep_all: ONE flat 1D launch, no dead blocks -------------------
#define TSEG 5
#define PSEG 5
struct PrepArgs {
  const float* tsrc[TSEG];
  __bf16*      tdst[TSEG];
  int tstart[TSEG + 1];
  int ktiles[TSEG];            // K/64
  const float* psrc[PSEG];
  __bf16*      pdst[PSEG];
  int pstart[PSEG + 1];        // block starts (after tblocks)
  int pchunks[PSEG];           // total 8-elem chunks in segment
  int kdiv8[PSEG];
  int N[PSEG];                 // 1 = plain copy, else transpose inner stride
  int tblocks;
};

__global__ __launch_bounds__(256) void prep_all(PrepArgs a) {
  const int tid = threadIdx.x;
  const int b = blockIdx.x;
  __shared__ __bf16 lt[64 * 72];
  if (b < a.tblocks) {
    int s = 0;
    while (s < TSEG - 1 && b >= a.tstart[s + 1]) ++s;
    const int idx = b - a.tstart[s];
    const int kt = idx % a.ktiles[s];
    const int c  = idx / a.ktiles[s];
    const int K  = a.ktiles[s] * 64;
    const float* src = a.tsrc[s] + (size_t)c * K * 64 + (size_t)kt * 64 * 64;
    __bf16*      dst = a.tdst[s] + (size_t)c * 64 * K + kt * 64;
    const int r = tid >> 4, c4 = (tid & 15) * 4;
#pragma unroll
    for (int it = 0; it < 4; ++it) {
      int k = r + it * 16;
      float4 v = *(const float4*)(src + (size_t)k * 64 + c4);
      lt[(c4 + 0) * 72 + k] = (__bf16)v.x;
      lt[(c4 + 1) * 72 + k] = (__bf16)v.y;
      lt[(c4 + 2) * 72 + k] = (__bf16)v.z;
      lt[(c4 + 3) * 72 + k] = (__bf16)v.w;
    }
    __syncthreads();
    const int n = tid >> 3, i = tid & 7;
#pragma unroll
    for (int it = 0; it < 2; ++it) {
      int nn = n + it * 32;
      *(uint4*)(dst + (size_t)nn * K + i * 8) = *(const uint4*)&lt[nn * 72 + i * 8];
    }
  } else {
    const int bb = b - a.tblocks;
    int s = 0;
    while (s < PSEG - 1 && bb >= a.pstart[s + 1]) ++s;
    const int lb  = bb - a.pstart[s];
    const int nch = a.pchunks[s];
    const int kc  = a.kdiv8[s];
    const int N   = a.N[s];
#pragma unroll
    for (int j = 0; j < 4; ++j) {
      const int li = (lb * 4 + j) * 256 + tid;
      if (li >= nch) break;
      if (N == 1) {
        const float4* src = (const float4*)a.psrc[s] + (size_t)li * 2;
        float4 v0 = src[0], v1 = src[1];
        *(uint4*)(a.pdst[s] + (size_t)li * 8) = __builtin_bit_cast(uint4, cvt8(v0, v1));
      } else {
        int rn = li / kc;
        int k0 = (li - rn * kc) * 8;
        int cc = rn / N;
        int n  = rn - cc * N;
        const float* src = a.psrc[s] + ((size_t)cc * kc * 8 + k0) * N + n;
        bf16x8 r;
#pragma unroll
        for (int jj = 0; jj < 8; ++jj) r[jj] = (__bf16)src[(size_t)jj * N];
        *(uint4*)(a.pdst[s] + (size_t)rn * kc * 8 + k0) = __builtin_bit_cast(uint4, r);
      }
    }
  }
}

// ============================== launch =======================================
extern "C" void kernel_launch(void* const* d_in, const int* in_sizes, int n_in,
                              void* d_out, int out_size, void* d_ws, size_t ws_size,
                              hipStream_t stream) {
  const float* xf   = (const float*)d_in[0];
  const float* pW1f = (const float*)d_in[1];
  const float* pb1f = (const float*)d_in[2];
  const float* pW2f = (const float*)d_in[3];
  const float* pb2f = (const float*)d_in[4];
  const float* pW3f = (const float*)d_in[5];
  const float* pb3f = (const float*)d_in[6];
  const float* nW1f = (const float*)d_in[7];
  const float* nb1f = (const float*)d_in[8];
  const float* nW2f = (const float*)d_in[9];
  const float* nb2f = (const float*)d_in[10];
  const float* nW3f = (const float*)d_in[11];
  const float* nb3f = (const float*)d_in[12];
  const float* cW1f = (const float*)d_in[13];
  const float* cb1f = (const float*)d_in[14];
  const float* cW2f = (const float*)d_in[15];
  const float* cb2f = (const float*)d_in[16];
  const float* cW3f = (const float*)d_in[17];
  const float* cb3f = (const float*)d_in[18];

  float* out_emb = (float*)d_out;
  float* out_con = out_emb + (size_t)B_ * E_ * C_;

  const int cx   = B_ * IN_;          // 6291456
  const int cW1c = C_ * IN_ * H_;     // 3145728
  const int cW2c = C_ * H_ * H_;      // 262144
  const int cW3c = C_ * H_ * E_;      // 65536
  const int ccW1 = C_ * 2 * E_ * H_;  // 131072
  const int ccW3 = C_ * H_;           // 4096

  __bf16* w = (__bf16*)d_ws;
  size_t o = 0;
  __bf16* xw   = w + o; o += cx;
  __bf16* pw1t = w + o; o += cW1c;
  __bf16* nw1t = w + o; o += cW1c;
  __bf16* pw2t = w + o; o += cW2c;
  __bf16* nw2t = w + o; o += cW2c;
  __bf16* cw2t = w + o; o += cW2c;
  __bf16* pw3t = w + o; o += cW3c;
  __bf16* nw3t = w + o; o += cW3c;
  __bf16* cw1t = w + o; o += ccW1;
  __bf16* cw3w = w + o; o += ccW3;

  PrepArgs a;
  int tb = 0, pb = 0;
  {
    const float* tsrc[TSEG] = {pW1f, nW1f, pW2f, nW2f, cW2f};
    __bf16*      tdst[TSEG] = {pw1t, nw1t, pw2t, nw2t, cw2t};
    const int    tk[TSEG]   = {12,   12,   1,    1,    1};
    for (int i = 0; i < TSEG; ++i) {
      a.tsrc[i] = tsrc[i]; a.tdst[i] = tdst[i]; a.ktiles[i] = tk[i];
      a.tstart[i] = tb;
      tb += tk[i] * C_;
    }
    a.tstart[TSEG] = tb;
    a.tblocks = tb;

    const float* psrc[PSEG] = {xf, cW3f, pW3f, nW3f, cW1f};
    __bf16*      pdst[PSEG] = {xw, cw3w, pw3t, nw3t, cw1t};
    const int    pKs[PSEG]  = {0,  0,    64,   64,   32};
    const int    pNs[PSEG]  = {1,  1,    16,   16,   64};
    const int    pels[PSEG] = {cx, ccW3, cW3c, cW3c, ccW1};
    for (int i = 0; i < PSEG; ++i) {
      a.psrc[i] = psrc[i]; a.pdst[i] = pdst[i];
      a.pchunks[i] = pels[i] / 8;
      a.kdiv8[i] = (pNs[i] == 1) ? (pels[i] / 8) : (pKs[i] / 8);
      a.N[i] = pNs[i];
      a.pstart[i] = pb;
      pb += (pels[i] / 8 + 1023) / 1024;   // 256 threads x 4 chunks per block
    }
    a.pstart[PSEG] = pb;
  }
  prep_all<<<tb + pb, 256, 0, stream>>>(a);

  dim3 grid(B_ / BM_, C_);
  cb_fused_t<<<grid, 256, 0, stream>>>(xw,
      pw1t, pb1f, pw2t, pb2f, pw3t, pb3f,
      nw1t, nb1f, nw2t, nb2f, nw3t, nb3f,
      cw1t, cb1f, cw2t, cb2f, cw3w, cb3f,
      out_emb, out_con);
}